// Round 5
// baseline (148.807 us; speedup 1.0000x reference)
//
#include <hip/hip_runtime.h>
#include <hip/hip_fp16.h>

#define DIM   160
#define DIM2  25600
#define TY    16
#define TX    32
#define TZ    20
#define HY    22            // TY + 6
#define HX    38            // TX + 6
#define NSL   26            // TZ + 6
#define NSITE (HY * HX)     // 836
#define YCC   (TY * HX)     // 608
#define NVOX_D 16384000.0

#define W0 0.03663285f
#define W1 0.11128076f
#define W2 0.21674532f
#define W3 0.27068213f

__global__ void ssim_zero_acc(double* acc) {
    if (threadIdx.x == 0 && blockIdx.x == 0) acc[0] = 0.0;
}

__global__ __launch_bounds__(128, 3) void ssim_main(const float* __restrict__ P,
                                                    const float* __restrict__ T,
                                                    double* __restrict__ acc) {
    const float Wk[7] = {W0, W1, W2, W3, W2, W1, W0};

    __shared__ float2 sPT[2 * NSITE];   // (p,t) interleaved, double-buffered
    __shared__ float  yc[5 * YCC];      // y-conv output: [ch][16][38]
    __shared__ float  red[2];

    const int tid = threadIdx.x;
    int bid = blockIdx.x;
    int b  = bid / 400;  int r  = bid - b * 400;   // 8 zc * 10 ty * 5 tx
    int zc = r / 50;     int r2 = r - zc * 50;
    int ty = r2 / 5;     int tx = r2 - ty * 5;

    const int base = b * (DIM * DIM * DIM);
    const int z0 = zc * TZ, y0 = ty * TY - 3, x0 = tx * TX - 3;

    // ---- hoisted staging sites: u = tid + 128k, k<7 (836 = 6*128 + 68) ----
    int  gofs[7];
    bool ld[7], st[7];
#pragma unroll
    for (int k = 0; k < 7; ++k) {
        int u = tid + 128 * k;
        st[k] = (u < NSITE);
        int y = u / HX, x = u - y * HX;
        int gy = y0 + y, gx = x0 + x;
        ld[k] = st[k] & ((unsigned)gy < (unsigned)DIM) & ((unsigned)gx < (unsigned)DIM);
        gofs[k] = gy * DIM + gx;
    }

    // ---- y-conv 2x2 tasks: t -> rows 2yp,2yp+1, cols 2xq,2xq+1 (152 tasks) ----
    // ---- x-conv: cy = tid/8 (16 rows), jq = tid%8 -> outputs 4jq..4jq+3 ----
    const int cy = tid >> 3, jq = tid & 7;
    const int xb = cy * HX + 4 * jq;

    const __half2 hz = __float2half2_rn(0.f);
    __half2 azA[5][7], azB[5][7];
#pragma unroll
    for (int c = 0; c < 5; ++c)
#pragma unroll
        for (int j = 0; j < 7; ++j) { azA[c][j] = hz; azB[c][j] = hz; }

    float lsum = 0.f;
    float rp[7], rt[7];

    // ---- prologue: slice zs = z0-3 into buffer 0 ----
    {
        int zs = z0 - 3;
        bool zok = (unsigned)zs < (unsigned)DIM;
        const float* Pp = P + base + zs * DIM2;
        const float* Tp = T + base + zs * DIM2;
#pragma unroll
        for (int k = 0; k < 7; ++k) {
            rp[k] = 0.f; rt[k] = 0.f;
            if (zok && ld[k]) { rp[k] = Pp[gofs[k]]; rt[k] = Tp[gofs[k]]; }
        }
#pragma unroll
        for (int k = 0; k < 7; ++k)
            if (st[k]) sPT[tid + 128 * k] = make_float2(rp[k], rt[k]);
    }
    __syncthreads();

    auto ytask = [&](int t, const float2* cur) {
        int yp = t / 19, xq = t - yp * 19;
        const float2* src = cur + (2 * yp) * HX + 2 * xq;
        float A[5][2], Bv[5][2];
#pragma unroll
        for (int c = 0; c < 5; ++c)
#pragma unroll
            for (int e = 0; e < 2; ++e) { A[c][e] = 0.f; Bv[c][e] = 0.f; }
#pragma unroll
        for (int k = 0; k < 8; ++k) {
            float4 q = *(const float4*)(src + k * HX);
            float pa = q.x, ta = q.y, pb = q.z, tb = q.w;
            float p2a = pa * pa, t2a = ta * ta, pta = pa * ta;
            float p2b = pb * pb, t2b = tb * tb, ptb = pb * tb;
            if (k < 7) {
                float w = Wk[k];
                A[0][0] = fmaf(w, pa,  A[0][0]); A[0][1] = fmaf(w, pb,  A[0][1]);
                A[1][0] = fmaf(w, ta,  A[1][0]); A[1][1] = fmaf(w, tb,  A[1][1]);
                A[2][0] = fmaf(w, p2a, A[2][0]); A[2][1] = fmaf(w, p2b, A[2][1]);
                A[3][0] = fmaf(w, t2a, A[3][0]); A[3][1] = fmaf(w, t2b, A[3][1]);
                A[4][0] = fmaf(w, pta, A[4][0]); A[4][1] = fmaf(w, ptb, A[4][1]);
            }
            if (k >= 1) {
                float w = Wk[k - 1];
                Bv[0][0] = fmaf(w, pa,  Bv[0][0]); Bv[0][1] = fmaf(w, pb,  Bv[0][1]);
                Bv[1][0] = fmaf(w, ta,  Bv[1][0]); Bv[1][1] = fmaf(w, tb,  Bv[1][1]);
                Bv[2][0] = fmaf(w, p2a, Bv[2][0]); Bv[2][1] = fmaf(w, p2b, Bv[2][1]);
                Bv[3][0] = fmaf(w, t2a, Bv[3][0]); Bv[3][1] = fmaf(w, t2b, Bv[3][1]);
                Bv[4][0] = fmaf(w, pta, Bv[4][0]); Bv[4][1] = fmaf(w, ptb, Bv[4][1]);
            }
        }
        int wb = (2 * yp) * HX + 2 * xq;
#pragma unroll
        for (int c = 0; c < 5; ++c) {
            *(float2*)&yc[c * YCC + wb]      = make_float2(A[c][0],  A[c][1]);
            *(float2*)&yc[c * YCC + wb + HX] = make_float2(Bv[c][0], Bv[c][1]);
        }
    };

    for (int i = 0; i < NSL; ++i) {
        const float2* cur = sPT + (i & 1) * NSITE;
        const bool hn = (i + 1 < NSL);

        // ---- prefetch next slice into regs ----
        if (hn) {
            int zs = z0 + i - 2;
            bool zok = (unsigned)zs < (unsigned)DIM;
            const float* Pp = P + base + zs * DIM2;
            const float* Tp = T + base + zs * DIM2;
#pragma unroll
            for (int k = 0; k < 7; ++k) {
                rp[k] = 0.f; rt[k] = 0.f;
                if (zok && ld[k]) { rp[k] = Pp[gofs[k]]; rt[k] = Tp[gofs[k]]; }
            }
        }

        // ---- y-conv: 152 2x2 tasks on 128 threads ----
        ytask(tid, cur);
        if (tid < 24) ytask(tid + 128, cur);
        __syncthreads();

        // ---- x-conv: 4 outputs per thread, 5 b64 reads per channel ----
        float s[5][4];
#pragma unroll
        for (int c = 0; c < 5; ++c) {
            const float* ypr = &yc[c * YCC + xb];
            float2 v0 = *(const float2*)(ypr);
            float2 v1 = *(const float2*)(ypr + 2);
            float2 v2 = *(const float2*)(ypr + 4);
            float2 v3 = *(const float2*)(ypr + 6);
            float2 v4 = *(const float2*)(ypr + 8);
            float v[10] = {v0.x, v0.y, v1.x, v1.y, v2.x, v2.y, v3.x, v3.y, v4.x, v4.y};
#pragma unroll
            for (int o = 0; o < 4; ++o) {
                float sv = 0.f;
#pragma unroll
                for (int k = 0; k < 7; ++k) sv = fmaf(Wk[k], v[o + k], sv);
                s[c][o] = sv;
            }
        }

        // ---- z scatter: two half2 pipes (voxels 0,1 and 2,3) ----
#pragma unroll
        for (int c = 0; c < 5; ++c) {
            __half2 a2 = __floats2half2_rn(s[c][0], s[c][1]);
            __half2 b2 = __floats2half2_rn(s[c][2], s[c][3]);
#pragma unroll
            for (int j = 0; j < 7; ++j) {
                __half2 w2 = __float2half2_rn(Wk[6 - j]);
                azA[c][j] = __hfma2(w2, a2, azA[c][j]);
                azB[c][j] = __hfma2(w2, b2, azB[c][j]);
            }
        }

        if (i >= 6) {
#pragma unroll
            for (int pipe = 0; pipe < 2; ++pipe) {
                __half2 h0 = pipe ? azB[0][0] : azA[0][0];
                __half2 h1 = pipe ? azB[1][0] : azA[1][0];
                __half2 h2 = pipe ? azB[2][0] : azA[2][0];
                __half2 h3 = pipe ? azB[3][0] : azA[3][0];
                __half2 h4 = pipe ? azB[4][0] : azA[4][0];
                {
                    float mp = __low2float(h0), mt = __low2float(h1);
                    float ep2 = __low2float(h2), et2 = __low2float(h3), ept = __low2float(h4);
                    float mp2 = mp * mp, mt2 = mt * mt, mpt = mp * mt;
                    float num = fmaf(2.f, mpt, 1e-4f) * fmaf(2.f, ept - mpt, 9e-4f);
                    float den = (mp2 + mt2 + 1e-4f) * ((ep2 - mp2) + (et2 - mt2) + 9e-4f);
                    lsum += num * __builtin_amdgcn_rcpf(den);
                }
                {
                    float mp = __high2float(h0), mt = __high2float(h1);
                    float ep2 = __high2float(h2), et2 = __high2float(h3), ept = __high2float(h4);
                    float mp2 = mp * mp, mt2 = mt * mt, mpt = mp * mt;
                    float num = fmaf(2.f, mpt, 1e-4f) * fmaf(2.f, ept - mpt, 9e-4f);
                    float den = (mp2 + mt2 + 1e-4f) * ((ep2 - mp2) + (et2 - mt2) + 9e-4f);
                    lsum += num * __builtin_amdgcn_rcpf(den);
                }
            }
        }

        // ---- shift z pipes ----
#pragma unroll
        for (int c = 0; c < 5; ++c) {
#pragma unroll
            for (int j = 0; j < 6; ++j) { azA[c][j] = azA[c][j + 1]; azB[c][j] = azB[c][j + 1]; }
            azA[c][6] = hz; azB[c][6] = hz;
        }

        // ---- commit next slice ----
        if (hn) {
            float2* nxt = sPT + ((i + 1) & 1) * NSITE;
#pragma unroll
            for (int k = 0; k < 7; ++k)
                if (st[k]) nxt[tid + 128 * k] = make_float2(rp[k], rt[k]);
        }
        __syncthreads();
    }

    // ---- block reduction (2 waves), one f64 atomic ----
#pragma unroll
    for (int off = 32; off > 0; off >>= 1) lsum += __shfl_down(lsum, off);
    if ((tid & 63) == 0) red[tid >> 6] = lsum;
    __syncthreads();
    if (tid == 0) atomicAdd(acc, (double)(red[0] + red[1]));
}

__global__ void ssim_finalize(const double* __restrict__ acc, float* __restrict__ out) {
    if (threadIdx.x == 0 && blockIdx.x == 0)
        out[0] = 1.f - (float)(acc[0] / NVOX_D);
}

extern "C" void kernel_launch(void* const* d_in, const int* in_sizes, int n_in,
                              void* d_out, int out_size, void* d_ws, size_t ws_size,
                              hipStream_t stream) {
    const float* P = (const float*)d_in[0];
    const float* T = (const float*)d_in[1];
    float* out = (float*)d_out;
    double* acc = (double*)d_ws;

    ssim_zero_acc<<<1, 64, 0, stream>>>(acc);
    ssim_main<<<4 * 8 * 10 * 5, 128, 0, stream>>>(P, T, acc);
    ssim_finalize<<<1, 64, 0, stream>>>(acc, out);
}